// Round 9
// baseline (336.463 us; speedup 1.0000x reference)
//
#include <hip/hip_runtime.h>
#include <hip/hip_bf16.h>

// USM sharpen: 4 passes, each an x-blur (contraction along the FAST dim) via
// band-matrix MFMA, writing the result TRANSPOSED. Two such passes = 2D blur.
//   P1: img  f32[y][x] --xblur--> t1 bf16[x][y]
//   P2: t1  bf16[x][y] --xblur--> res bf16[y][x] = img - blur2D
//   P3: res bf16[y][x] --mask+xblur--> t3 bf16[x][y]   (t1 slot reused)
//   P4: t3  bf16[x][y] --xblur--> out f32[y][x] = img + sm*(sharp-img)
// Because contraction is the fast dim, MFMA B-fragments (8 contiguous bf16)
// load STRAIGHT from global as 16B/lane b128 -- no data LDS, no stage, no
// transpose tile, no bank conflicts. Only LDS: 3KB W band, built once.
// Band: input v in [v0-32, v0+64) (16B-aligned since v0%16==0), weights
// W[m][k] = g[k-m-7] (zero-padded), so out[v0+m] = sum_t g[t] in[v0+m+t-25].
// A/B/C fragment indexing identical to the round-7-verified kernel
// (A row m and D row = 4g+q on the A side, D col = lane&15 on the B side;
// same (g,j)->k map on A and B so any in-group k-permutation cancels).
// Reflect padding: only v-tiles with v0<32 or v0>448 (5 of 32, wave-uniform)
// take a scalar-load reflect path.

typedef __attribute__((ext_vector_type(8))) short bf16x8;
typedef __attribute__((ext_vector_type(4))) float f32x4;

constexpr int IMG = 512, NIMG = 48, K = 51;

__device__ __forceinline__ float bf2f(unsigned short u) {
    return __builtin_bit_cast(float, (unsigned)u << 16);
}
__device__ __forceinline__ unsigned short f2bf(float f) {
    unsigned u = __builtin_bit_cast(unsigned, f);
    u += 0x7FFF + ((u >> 16) & 1);  // RNE, finite inputs only
    return (unsigned short)(u >> 16);
}
__device__ __forceinline__ int refl(int i) {
    i = i < 0 ? -i : i;
    return i >= IMG ? 2 * IMG - 2 - i : i;
}

// SRCB: src elem 0=f32, 1=bf16.  LOADM 1: mask(|v|*255>10) applied to B elems
// (bf16 bit-compare (u&0x7FFF)>0x3D20 is EXACT for bf16 inputs: bf16*255 is
// exact in f32, and the first bf16 magnitude with |v|*255>10 is 0x3D21).
// STOREM: 0 blur->bf16 dst; 1 img-blur->bf16 dst; 2 final f32 dst.
template <int SRCB, int LOADM, int STOREM>
__global__ __launch_bounds__(256) void xblur_kern(const void* __restrict__ srcv,
                                                  const float* __restrict__ img,
                                                  const unsigned short* __restrict__ res,
                                                  void* __restrict__ dstv,
                                                  const float* __restrict__ k1d) {
    __shared__ unsigned short wb[16 * 96];  // W band, 3 KB
    const int tid = threadIdx.x, lane = tid & 63;
    const int wv = __builtin_amdgcn_readfirstlane(tid >> 6);
    const int m16 = lane & 15, g = lane >> 4;

    // ---- build W[m][k] = g[k-m-7] once (256 threads x 6 = 1536 elems) ----
#pragma unroll
    for (int e = 0; e < 6; ++e) {
        const int idx = tid + e * 256;
        const int mm = idx / 96, kk = idx - mm * 96;
        const int t = kk - mm - 7;
        wb[idx] = (t >= 0 && t < K) ? f2bf(k1d[t]) : (unsigned short)0;
    }
    __syncthreads();

    bf16x8 a[3];
#pragma unroll
    for (int rs = 0; rs < 3; ++rs)
        a[rs] = *(const bf16x8*)&wb[m16 * 96 + rs * 32 + g * 8];  // 16B aligned

    const int u0 = blockIdx.x * 64;                 // 4 u-tiles per wave
    const int v0 = (blockIdx.y * 4 + wv) * 16;      // 1 v-tile per wave
    const size_t base = (size_t)blockIdx.z * (IMG * IMG);
    const bool edge = (v0 < 32) || (v0 > 448);      // band leaves [0,512)

    f32x4 acc[4] = {{0.f, 0.f, 0.f, 0.f}, {0.f, 0.f, 0.f, 0.f},
                    {0.f, 0.f, 0.f, 0.f}, {0.f, 0.f, 0.f, 0.f}};

#pragma unroll
    for (int ut = 0; ut < 4; ++ut) {
        const size_t urow = base + (size_t)(u0 + ut * 16 + m16) * IMG;
#pragma unroll
        for (int rs = 0; rs < 3; ++rs) {
            const int vk = v0 - 32 + rs * 32 + g * 8;  // mult of 8 -> 16B aligned
            bf16x8 b;
            if (!edge) {
                if (SRCB) {
                    b = *(const bf16x8*)&((const unsigned short*)srcv)[urow + vk];
                } else {
                    const f32x4 f0 = *(const f32x4*)&((const float*)srcv)[urow + vk];
                    const f32x4 f1 = *(const f32x4*)&((const float*)srcv)[urow + vk + 4];
#pragma unroll
                    for (int j = 0; j < 4; ++j) {
                        b[j] = (short)f2bf(f0[j]);
                        b[j + 4] = (short)f2bf(f1[j]);
                    }
                }
            } else {
#pragma unroll
                for (int j = 0; j < 8; ++j) {
                    const int vv = refl(vk + j);
                    b[j] = SRCB ? (short)((const unsigned short*)srcv)[urow + vv]
                                : (short)f2bf(((const float*)srcv)[urow + vv]);
                }
            }
            if (LOADM == 1) {
#pragma unroll
                for (int j = 0; j < 8; ++j) {
                    const unsigned short uu = (unsigned short)b[j];
                    b[j] = (short)(((uu & 0x7FFFu) > 0x3D20u) ? 0x3F80 : 0);
                }
            }
            acc[ut] = __builtin_amdgcn_mfma_f32_16x16x32_bf16(a[rs], b, acc[ut], 0, 0, 0);
        }
    }

    // ---- transposed store: D row 4g+q -> v, D col m16 -> u (16-lane 32B runs) ----
#pragma unroll
    for (int ut = 0; ut < 4; ++ut) {
        const int u = u0 + ut * 16 + m16;
#pragma unroll
        for (int q = 0; q < 4; ++q) {
            const size_t di = base + (size_t)(v0 + 4 * g + q) * IMG + u;
            const float bv = acc[ut][q];
            if (STOREM == 0) {
                ((unsigned short*)dstv)[di] = f2bf(bv);
            } else if (STOREM == 1) {
                ((unsigned short*)dstv)[di] = f2bf(img[di] - bv);
            } else {
                const float iv = img[di];
                const float rv = bf2f(res[di]);
                float sharp = fmaf(0.5f, rv, iv);
                sharp = fminf(fmaxf(sharp, 0.f), 1.f);
                ((float*)dstv)[di] = fmaf(bv, sharp - iv, iv);  // img + sm*(sharp-img)
            }
        }
    }
}

extern "C" void kernel_launch(void* const* d_in, const int* in_sizes, int n_in,
                              void* d_out, int out_size, void* d_ws, size_t ws_size,
                              hipStream_t stream) {
    (void)in_sizes; (void)n_in; (void)out_size; (void)ws_size;
    const float* img = (const float*)d_in[0];
    const float* k1d = (const float*)d_in[1];
    float* out = (float*)d_out;
    unsigned short* t1 = (unsigned short*)d_ws;                             // 25165824 B
    unsigned short* rs = (unsigned short*)d_ws + (size_t)NIMG * IMG * IMG;  // 25165824 B

    const dim3 grid(IMG / 64, IMG / 64, NIMG);  // (8, 8, 48) = 3072 blocks x 256 thr

    xblur_kern<0, 0, 0><<<grid, 256, 0, stream>>>(img, nullptr, nullptr, t1, k1d);
    xblur_kern<1, 0, 1><<<grid, 256, 0, stream>>>(t1, img, nullptr, rs, k1d);   // rs = residual
    xblur_kern<1, 1, 0><<<grid, 256, 0, stream>>>(rs, nullptr, nullptr, t1, k1d);
    xblur_kern<1, 0, 2><<<grid, 256, 0, stream>>>(t1, img, rs, out, k1d);       // final
}

// Round 10
// 103.628 us; speedup vs baseline: 3.2468x; 3.2468x over previous
//
#include <hip/hip_runtime.h>
#include <hip/hip_bf16.h>

// USM sharpen, fused 2-kernel MFMA version (R8 redone with its 3 failures fixed):
//   K1 (PASS 0): img f32 --[hblur -> H(LDS) -> vblur]--> res bf16 = img - blur2D
//   K2 (PASS 1): mask(res) --[hblur -> H(LDS) -> vblur]--> sm; out = img + sm*(sharp-img)
// Per block: 64x64 output tile.
//   stage st[128 rows][136p] bf16, row-major: y = y0-33+s (s<122 data, 122-127 clamp),
//     x = x0-32+c, c in [0,128). Row-dense b128 writes (min-time banks).
//   MFMA1 (hblur): out H[x'][s], x' = x-32-? -> taps x = x0 + x' + t - 25, i.e.
//     c = x' + t + 7. 2 K-slices k' in [0,64) at c = 16xs+8+k', W1[i][k'] = g[k'+1-i];
//     missing taps corrected: i=0/t=0 (c=16xs+7), i=15/t=50 (c=16xs+72).
//   MFMA2 (vblur): taps s = y' + t + 8 (y'=y-y0). slices s = 16ys+8+k', W0[i][k']=g[k'-i];
//     corrections: i=14/t=50 (s=16ys+72), i=15/t=49,50 (s=16ys+72,73).
//     All corrected/frag reads hit s<=121 = REAL data (clamp rows never read).
// Fragment indexing identical to the R7-verified kernel (A row=m16, B col=m16,
// D col=m16 / row=4g+q, same (rs,g,j)->k map on A and B).
// W bands (2x16x64 bf16 = 4KB) built in LDS aliasing H; frags->regs, barrier, then
// H-writes may clobber. LDS total 34816+17408 = 52224 B -> 3 blocks/CU.
// Chunked XCD swizzle (3072 = 8*384) so halo-sharing neighbor tiles share an L2.

typedef __attribute__((ext_vector_type(8))) short bf16x8;
typedef __attribute__((ext_vector_type(4))) float f32x4;

constexpr int IMG = 512, NIMG = 48, K = 51;
constexpr int SP = 136;      // stage pitch (elems): 68 dwords % 32 = 4 -> bank spread
constexpr int YP = 136;      // H pitch
constexpr int SROWS = 128;   // staged rows: 122 data + 6 clamp
constexpr int SDATA = 122;

__device__ __forceinline__ float bf2f(unsigned short u) {
    return __builtin_bit_cast(float, (unsigned)u << 16);
}
__device__ __forceinline__ unsigned short f2bf(float f) {
    unsigned u = __builtin_bit_cast(unsigned, f);
    u += 0x7FFF + ((u >> 16) & 1);  // RNE, finite inputs only
    return (unsigned short)(u >> 16);
}
__device__ __forceinline__ int refl(int i) {
    i = i < 0 ? -i : i;
    return i >= IMG ? 2 * IMG - 2 - i : i;
}

template <int PASS>  // 0: img -> res ; 1: res -> out
__global__ __launch_bounds__(512, 6) void usm_kern(const float* __restrict__ img,
                                                   unsigned short* __restrict__ resbuf,
                                                   float* __restrict__ out,
                                                   const float* __restrict__ k1d) {
    __shared__ unsigned short st[SROWS * SP];  // 34816 B
    __shared__ unsigned short Hl[64 * YP];     // 17408 B; first 2048 elems alias W bands

    const int tid = threadIdx.x, lane = tid & 63;
    const int wv = __builtin_amdgcn_readfirstlane(tid >> 6);
    const int m16 = lane & 15, g = lane >> 4;

    const int id = blockIdx.x;
    const int sw = (id & 7) * 384 + (id >> 3);  // bijective: 3072 = 8*384
    const int bz = sw >> 6, r6 = sw & 63, byy = r6 >> 3, bxx = r6 & 7;
    const int x0 = bxx * 64, y0 = byy * 64;
    const size_t base = (size_t)bz * (IMG * IMG);

    // ---- phase A: W bands (W0 vblur g[k'-i] @0, W1 hblur g[k'+1-i] @1024) + stage ----
#pragma unroll
    for (int e = 0; e < 4; ++e) {
        const int idx = tid + e * 512;           // 2048 band elems
        const int band = idx >> 10, rem = idx & 1023;
        const int mm = rem >> 6, kk = rem & 63;
        const int t = kk - mm + band;
        Hl[idx] = ((unsigned)t < (unsigned)K) ? f2bf(k1d[t]) : (unsigned short)0;
    }

    const bool xedge = (bxx == 0) | (bxx == 7);
    const int r0 = tid >> 4, c8 = (tid & 15) * 8;
#pragma unroll
    for (int j = 0; j < 4; ++j) {
        const int s = r0 + 32 * j;
        const int y = refl(y0 - 33 + min(s, SDATA - 1));
        const size_t rowb = base + (size_t)y * IMG;
        unsigned pk[4];
        if (PASS == 0) {
            float v[8];
            if (!xedge) {
                const f32x4 f0 = *(const f32x4*)&img[rowb + (x0 - 32 + c8)];
                const f32x4 f1 = *(const f32x4*)&img[rowb + (x0 - 32 + c8 + 4)];
#pragma unroll
                for (int e2 = 0; e2 < 4; ++e2) { v[e2] = f0[e2]; v[e2 + 4] = f1[e2]; }
            } else {
#pragma unroll
                for (int e2 = 0; e2 < 8; ++e2) v[e2] = img[rowb + refl(x0 - 32 + c8 + e2)];
            }
#pragma unroll
            for (int w = 0; w < 4; ++w)
                pk[w] = (unsigned)f2bf(v[2 * w]) | ((unsigned)f2bf(v[2 * w + 1]) << 16);
        } else {
            unsigned short u[8];
            if (!xedge) {
                const uint4 q4 = *(const uint4*)&resbuf[rowb + (x0 - 32 + c8)];
                const unsigned ww[4] = {q4.x, q4.y, q4.z, q4.w};
#pragma unroll
                for (int w = 0; w < 4; ++w) {
                    u[2 * w] = (unsigned short)ww[w];
                    u[2 * w + 1] = (unsigned short)(ww[w] >> 16);
                }
            } else {
#pragma unroll
                for (int e2 = 0; e2 < 8; ++e2) u[e2] = resbuf[rowb + refl(x0 - 32 + c8 + e2)];
            }
#pragma unroll
            for (int w = 0; w < 4; ++w) {  // mask(|res|*255>10): exact bf16 bit-compare (R9-verified)
                const unsigned lo = ((u[2 * w]     & 0x7FFFu) > 0x3D20u) ? 0x3F80u : 0u;
                const unsigned hi = ((u[2 * w + 1] & 0x7FFFu) > 0x3D20u) ? 0x3F80u : 0u;
                pk[w] = lo | (hi << 16);
            }
        }
        *(uint4*)&st[s * SP + c8] = make_uint4(pk[0], pk[1], pk[2], pk[3]);
    }
    __syncthreads();

    // ---- phase B: A-fragments (regs) + exact scalar tap weights ----
    bf16x8 a_v[2], a_h[2];
#pragma unroll
    for (int rs = 0; rs < 2; ++rs) {
        a_v[rs] = *(const bf16x8*)&Hl[m16 * 64 + rs * 32 + 8 * g];
        a_h[rs] = *(const bf16x8*)&Hl[1024 + m16 * 64 + rs * 32 + 8 * g];
    }
    const float gg0 = k1d[0], gg49 = k1d[49], gg50 = k1d[50];
    __syncthreads();  // frags in regs; H-writes may now clobber the band region

    // ---- phase C: hblur -> Hl[x'][s]  (32 tiles, 4/wave, 2 MFMA + 2 corrections) ----
#pragma unroll
    for (int k4 = 0; k4 < 4; ++k4) {
        const int t = wv + 8 * k4;
        const int xs = t & 3, yt = t >> 2;
        const int n = 16 * yt + m16;  // B col = stage row s
        f32x4 acc = {0.f, 0.f, 0.f, 0.f};
#pragma unroll
        for (int rs = 0; rs < 2; ++rs) {
            const bf16x8 b = *(const bf16x8*)&st[n * SP + 16 * xs + 8 + 32 * rs + 8 * g];
            acc = __builtin_amdgcn_mfma_f32_16x16x32_bf16(a_h[rs], b, acc, 0, 0, 0);
        }
        if (g == 0) acc[0] = fmaf(gg0,  bf2f(st[n * SP + 16 * xs + 7]),  acc[0]);  // i=0,  t=0
        if (g == 3) acc[3] = fmaf(gg50, bf2f(st[n * SP + 16 * xs + 72]), acc[3]);  // i=15, t=50
#pragma unroll
        for (int q = 0; q < 4; ++q)
            Hl[(16 * xs + 4 * g + q) * YP + n] = f2bf(acc[q]);
    }
    __syncthreads();

    // ---- phase D: vblur + fused epilogue (16 tiles, 2/wave) ----
#pragma unroll
    for (int k2 = 0; k2 < 2; ++k2) {
        const int t = wv + 8 * k2;
        const int xs2 = t & 3, ys = t >> 2;
        const int xl = 16 * xs2 + m16;
        f32x4 acc = {0.f, 0.f, 0.f, 0.f};
#pragma unroll
        for (int rs = 0; rs < 2; ++rs) {
            const bf16x8 b = *(const bf16x8*)&Hl[xl * YP + 16 * ys + 8 + 32 * rs + 8 * g];
            acc = __builtin_amdgcn_mfma_f32_16x16x32_bf16(a_v[rs], b, acc, 0, 0, 0);
        }
        if (g == 3) {
            const float h72 = bf2f(Hl[xl * YP + 16 * ys + 72]);
            const float h73 = bf2f(Hl[xl * YP + 16 * ys + 73]);
            acc[2] = fmaf(gg50, h72, acc[2]);                   // i=14, t=50
            acc[3] = fmaf(gg49, h72, fmaf(gg50, h73, acc[3]));  // i=15, t=49,50
        }
        const int yl0 = 16 * ys + 4 * g;
#pragma unroll
        for (int q = 0; q < 4; ++q) {
            const size_t di = base + (size_t)(y0 + yl0 + q) * IMG + (x0 + xl);
            const float iv = img[di];  // L2-hot (tile just staged)
            if (PASS == 0) {
                resbuf[di] = f2bf(iv - acc[q]);
            } else {
                const float rv = bf2f(resbuf[di]);
                float sharp = fmaf(0.5f, rv, iv);
                sharp = fminf(fmaxf(sharp, 0.f), 1.f);
                out[di] = fmaf(acc[q], sharp - iv, iv);  // img + sm*(sharp-img)
            }
        }
    }
}

extern "C" void kernel_launch(void* const* d_in, const int* in_sizes, int n_in,
                              void* d_out, int out_size, void* d_ws, size_t ws_size,
                              hipStream_t stream) {
    (void)in_sizes; (void)n_in; (void)out_size; (void)ws_size;
    const float* img = (const float*)d_in[0];
    const float* k1d = (const float*)d_in[1];
    float* out = (float*)d_out;
    unsigned short* rs = (unsigned short*)d_ws;  // 48*512*512*2 = 25165824 B

    const dim3 grid(NIMG * 64);  // 3072 blocks x 512 threads

    usm_kern<0><<<grid, 512, 0, stream>>>(img, rs, out, k1d);
    usm_kern<1><<<grid, 512, 0, stream>>>(img, rs, out, k1d);
}

// Round 11
// 98.327 us; speedup vs baseline: 3.4219x; 1.0539x over previous
//
#include <hip/hip_runtime.h>
#include <hip/hip_bf16.h>

// USM sharpen, fused 2-kernel MFMA (R10 with the 3 identified parasites removed):
//   K1 (PASS 0): img f32 --[hblur -> H(LDS) -> vblur]--> res bf16 + mask u8
//   K2 (PASS 1): mask u8 --[hblur -> H(LDS) -> vblur]--> sm; out = img + sm*(sharp-img)
// Changes vs R10:
//   1. W-band fragments built in REGISTERS (9 predicated k1d gathers per slice:
//      a_v[rs][j] = g[32rs+8g+j-m16], a_h = same +1) -- kills the LDS band build,
//      its 16-way-conflict fragment loads (stride 64 shorts = 32 dwords == 0 mod 32),
//      and the phase-B barrier. 2 barriers total.
//   2. K1 writes mask(|res|*255>10) as u8; K2 stages u8 (half the bytes, no compare).
//   3. All global addressing as int32 offsets off per-image base pointers.
// Geometry unchanged (R10-verified): 64x64 tile, stage 128x136 bf16 row-major,
// H 64x136 bf16, 2 K-slices + exact scalar tap corrections, fragment indexing
// per the R7-verified convention, chunked XCD swizzle.

typedef __attribute__((ext_vector_type(8))) short bf16x8;
typedef __attribute__((ext_vector_type(4))) float f32x4;

constexpr int IMG = 512, NIMG = 48, K = 51;
constexpr int SP = 136;      // stage pitch: 68 dwords % 32 = 4 -> bank spread
constexpr int YP = 136;      // H pitch
constexpr int SROWS = 128;   // 122 data rows + 6 clamp
constexpr int SDATA = 122;

__device__ __forceinline__ float bf2f(unsigned short u) {
    return __builtin_bit_cast(float, (unsigned)u << 16);
}
__device__ __forceinline__ unsigned short f2bf(float f) {
    unsigned u = __builtin_bit_cast(unsigned, f);
    u += 0x7FFF + ((u >> 16) & 1);  // RNE, finite inputs only
    return (unsigned short)(u >> 16);
}
__device__ __forceinline__ int refl(int i) {
    i = i < 0 ? -i : i;
    return i >= IMG ? 2 * IMG - 2 - i : i;
}

template <int PASS>  // 0: img -> res+mask ; 1: mask -> out
__global__ __launch_bounds__(512, 6) void usm_kern(const float* __restrict__ img,
                                                   unsigned short* __restrict__ resbuf,
                                                   unsigned char* __restrict__ maskbuf,
                                                   float* __restrict__ out,
                                                   const float* __restrict__ k1d) {
    __shared__ unsigned short st[SROWS * SP];  // 34816 B
    __shared__ unsigned short Hl[64 * YP];     // 17408 B

    const int tid = threadIdx.x, lane = tid & 63;
    const int wv = __builtin_amdgcn_readfirstlane(tid >> 6);
    const int m16 = lane & 15, g = lane >> 4;

    const int id = blockIdx.x;
    const int sw = (id & 7) * 384 + (id >> 3);  // bijective XCD swizzle: 3072 = 8*384
    const int bz = sw >> 6, r6 = sw & 63, byy = r6 >> 3, bxx = r6 & 7;
    const int x0 = bxx * 64, y0 = byy * 64;
    const size_t base = (size_t)bz * (IMG * IMG);
    const float* __restrict__ imgb = img + base;
    unsigned short* __restrict__ resb = resbuf + base;
    unsigned char* __restrict__ maskb = maskbuf + base;
    float* __restrict__ outb = out + base;

    // ---- W bands in registers: a_v[rs][j]=g[32rs+8g+j-m16], a_h = idx+1 ----
    bf16x8 a_v[2], a_h[2];
#pragma unroll
    for (int rs = 0; rs < 2; ++rs) {
        float gt[9];
#pragma unroll
        for (int e = 0; e < 9; ++e) {
            const int t = 32 * rs + 8 * g + e - m16;
            gt[e] = ((unsigned)t < (unsigned)K) ? k1d[t] : 0.f;
        }
#pragma unroll
        for (int j = 0; j < 8; ++j) {
            a_v[rs][j] = (short)f2bf(gt[j]);
            a_h[rs][j] = (short)f2bf(gt[j + 1]);
        }
    }
    const float gg0 = k1d[0], gg49 = k1d[49], gg50 = k1d[50];  // uniform -> SGPR

    // ---- stage 128 rows x 128 cols (row-dense b128 writes) ----
    const bool xedge = (bxx == 0) | (bxx == 7);
    const int r0t = tid >> 4, c8 = (tid & 15) * 8;
#pragma unroll
    for (int j = 0; j < 4; ++j) {
        const int s = r0t + 32 * j;
        const int rowo = refl(y0 - 33 + min(s, SDATA - 1)) * IMG + (x0 - 32 + c8);
        unsigned pk[4];
        if (PASS == 0) {
            float v[8];
            if (!xedge) {
                const f32x4 f0 = *(const f32x4*)&imgb[rowo];
                const f32x4 f1 = *(const f32x4*)&imgb[rowo + 4];
#pragma unroll
                for (int e = 0; e < 4; ++e) { v[e] = f0[e]; v[e + 4] = f1[e]; }
            } else {
                const int rb = rowo - (x0 - 32 + c8);
#pragma unroll
                for (int e = 0; e < 8; ++e) v[e] = imgb[rb + refl(x0 - 32 + c8 + e)];
            }
#pragma unroll
            for (int w = 0; w < 4; ++w)
                pk[w] = (unsigned)f2bf(v[2 * w]) | ((unsigned)f2bf(v[2 * w + 1]) << 16);
        } else {
            unsigned char mb[8];
            if (!xedge) {
                const uint2 mv = *(const uint2*)&maskb[rowo];
#pragma unroll
                for (int e = 0; e < 4; ++e) {
                    mb[e] = (unsigned char)(mv.x >> (8 * e));
                    mb[e + 4] = (unsigned char)(mv.y >> (8 * e));
                }
            } else {
                const int rb = rowo - (x0 - 32 + c8);
#pragma unroll
                for (int e = 0; e < 8; ++e) mb[e] = maskb[rb + refl(x0 - 32 + c8 + e)];
            }
#pragma unroll
            for (int w = 0; w < 4; ++w)
                pk[w] = (mb[2 * w] ? 0x3F80u : 0u) | ((mb[2 * w + 1] ? 0x3F80u : 0u) << 16);
        }
        *(uint4*)&st[s * SP + c8] = make_uint4(pk[0], pk[1], pk[2], pk[3]);
    }
    __syncthreads();

    // ---- phase C: hblur -> Hl[x'][s] (32 tiles, 4/wave, 2 MFMA + 2 corrections) ----
#pragma unroll
    for (int k4 = 0; k4 < 4; ++k4) {
        const int t = wv + 8 * k4;
        const int xs = t & 3, yt = t >> 2;
        const int n = 16 * yt + m16;  // B col = stage row s
        f32x4 acc = {0.f, 0.f, 0.f, 0.f};
#pragma unroll
        for (int rs = 0; rs < 2; ++rs) {
            const bf16x8 b = *(const bf16x8*)&st[n * SP + 16 * xs + 8 + 32 * rs + 8 * g];
            acc = __builtin_amdgcn_mfma_f32_16x16x32_bf16(a_h[rs], b, acc, 0, 0, 0);
        }
        if (g == 0) acc[0] = fmaf(gg0,  bf2f(st[n * SP + 16 * xs + 7]),  acc[0]);  // i=0,  t=0
        if (g == 3) acc[3] = fmaf(gg50, bf2f(st[n * SP + 16 * xs + 72]), acc[3]);  // i=15, t=50
#pragma unroll
        for (int q = 0; q < 4; ++q)
            Hl[(16 * xs + 4 * g + q) * YP + n] = f2bf(acc[q]);
    }
    __syncthreads();

    // ---- phase D: vblur + fused epilogue (16 tiles, 2/wave) ----
#pragma unroll
    for (int k2 = 0; k2 < 2; ++k2) {
        const int t = wv + 8 * k2;
        const int xs2 = t & 3, ys = t >> 2;
        const int xl = 16 * xs2 + m16;
        f32x4 acc = {0.f, 0.f, 0.f, 0.f};
#pragma unroll
        for (int rs = 0; rs < 2; ++rs) {
            const bf16x8 b = *(const bf16x8*)&Hl[xl * YP + 16 * ys + 8 + 32 * rs + 8 * g];
            acc = __builtin_amdgcn_mfma_f32_16x16x32_bf16(a_v[rs], b, acc, 0, 0, 0);
        }
        if (g == 3) {
            const float h72 = bf2f(Hl[xl * YP + 16 * ys + 72]);
            const float h73 = bf2f(Hl[xl * YP + 16 * ys + 73]);
            acc[2] = fmaf(gg50, h72, acc[2]);                   // i=14, t=50
            acc[3] = fmaf(gg49, h72, fmaf(gg50, h73, acc[3]));  // i=15, t=49,50
        }
        const int yl0 = 16 * ys + 4 * g;
#pragma unroll
        for (int q = 0; q < 4; ++q) {
            const int di = (y0 + yl0 + q) * IMG + (x0 + xl);
            const float iv = imgb[di];  // L2-hot (tile just staged)
            if (PASS == 0) {
                const float rv = iv - acc[q];
                resb[di] = f2bf(rv);
                maskb[di] = (fabsf(rv) * 255.0f > 10.0f) ? 1 : 0;
            } else {
                const float rv = bf2f(resb[di]);
                float sharp = fmaf(0.5f, rv, iv);
                sharp = fminf(fmaxf(sharp, 0.f), 1.f);
                outb[di] = fmaf(acc[q], sharp - iv, iv);  // img + sm*(sharp-img)
            }
        }
    }
}

extern "C" void kernel_launch(void* const* d_in, const int* in_sizes, int n_in,
                              void* d_out, int out_size, void* d_ws, size_t ws_size,
                              hipStream_t stream) {
    (void)in_sizes; (void)n_in; (void)out_size; (void)ws_size;
    const float* img = (const float*)d_in[0];
    const float* k1d = (const float*)d_in[1];
    float* out = (float*)d_out;
    unsigned short* rs = (unsigned short*)d_ws;                                   // 25165824 B
    unsigned char* mk = (unsigned char*)d_ws + (size_t)NIMG * IMG * IMG * 2;      // 12582912 B

    const dim3 grid(NIMG * 64);  // 3072 blocks x 512 threads

    usm_kern<0><<<grid, 512, 0, stream>>>(img, rs, mk, out, k1d);
    usm_kern<1><<<grid, 512, 0, stream>>>(img, rs, mk, out, k1d);
}